// Round 6
// baseline (63.516 us; speedup 1.0000x reference)
//
#include <hip/hip_runtime.h>

#define SEQ 8192
#define DM 64

typedef __bf16 bfrag __attribute__((ext_vector_type(8)));   // MFMA A/B operand
typedef float  f4    __attribute__((ext_vector_type(4)));   // MFMA C/D operand

union PW { int w[4]; bfrag v; };

__device__ inline int pack_bf16(float a, float b) {
    const __bf16 ba = (__bf16)a, bb = (__bf16)b;
    const unsigned short ua = __builtin_bit_cast(unsigned short, ba);
    const unsigned short ub = __builtin_bit_cast(unsigned short, bb);
    return (int)(((unsigned)ub << 16) | (unsigned)ua);
}

// split a float into bf16 hi + bf16 lo (residual) for near-fp32 MFMA matmul
__device__ inline void split8(const float* __restrict__ p, bfrag& hi, bfrag& lo) {
    #pragma unroll
    for (int e = 0; e < 8; ++e) {
        const float v = p[e];
        const __bf16 h = (__bf16)v;
        hi[e] = h;
        lo[e] = (__bf16)(v - (float)h);
    }
}

__device__ __attribute__((always_inline)) inline void load_k(
    const __bf16* __restrict__ Kb, int kvb, int r, int g, bfrag (&k)[4]) {
    k[0] = *(const bfrag*)(Kb + (kvb + r) * DM + g * 8);
    k[1] = *(const bfrag*)(Kb + (kvb + r) * DM + 32 + g * 8);
    k[2] = *(const bfrag*)(Kb + (kvb + 16 + r) * DM + g * 8);
    k[3] = *(const bfrag*)(Kb + (kvb + 16 + r) * DM + 32 + g * 8);
}

__device__ __attribute__((always_inline)) inline void load_v(
    const __bf16* __restrict__ Vs, int t, int r, int g, bfrag (&v)[4]) {
    const __bf16* vb = Vs + t * 2048 + r * 32 + g * 8;
    v[0] = *(const bfrag*)(vb);
    v[1] = *(const bfrag*)(vb + 512);
    v[2] = *(const bfrag*)(vb + 1024);
    v[3] = *(const bfrag*)(vb + 1536);
}

// ---------------------------------------------------------------------------
// Kernel 1 (MFMA): 6144 wave-tasks = (matrix m, 16-row tile rt, dt quarter).
// 1536 blocks x 4 waves = 24 waves/CU. hi/lo bf16 split (~fp32 accuracy).
// q -> bf16 [S][64] (pre-scaled 1/8); k -> bf16 [S][64];
// v -> bf16 sigma-permuted tile-major Vs[S/32][64][32]:
//   row-local kv -> p = ((kv&15)>>2)*8 + (kv>>4)*4 + (kv&3)
// ---------------------------------------------------------------------------
__global__ __launch_bounds__(256) void qkv_proj(
    const float* __restrict__ x,
    const float* __restrict__ wq, const float* __restrict__ bq,
    const float* __restrict__ wk, const float* __restrict__ bk,
    const float* __restrict__ wv, const float* __restrict__ bv,
    __bf16* __restrict__ Qb, __bf16* __restrict__ Kb, __bf16* __restrict__ Vs)
{
    const int lane = threadIdx.x & 63;
    const int wid  = threadIdx.x >> 6;
    const int task = blockIdx.x * 4 + wid;      // 0..6143
    const int m    = task >> 11;                // 0..2
    const int rest = task & 2047;
    const int rt   = rest >> 2;                 // 0..511
    const int dt   = rest & 3;                  // 0..3
    const int rb   = rt << 4;                   // 16 rows
    const int g = lane >> 4, r = lane & 15;

    const float* w    = (m == 0) ? wq : (m == 1) ? wk : wv;
    const float* bias = (m == 0) ? bq : (m == 1) ? bk : bv;

    bfrag a_hi[2], a_lo[2];
    #pragma unroll
    for (int kh = 0; kh < 2; ++kh)
        split8(x + (rb + r) * DM + kh * 32 + g * 8, a_hi[kh], a_lo[kh]);

    const int c = dt * 16 + r;                  // output feature
    f4 acc = {0.f, 0.f, 0.f, 0.f};
    #pragma unroll
    for (int kh = 0; kh < 2; ++kh) {
        bfrag b_hi, b_lo;
        split8(w + c * DM + kh * 32 + g * 8, b_hi, b_lo);
        acc = __builtin_amdgcn_mfma_f32_16x16x32_bf16(a_hi[kh], b_hi, acc, 0, 0, 0);
        acc = __builtin_amdgcn_mfma_f32_16x16x32_bf16(a_lo[kh], b_hi, acc, 0, 0, 0);
        acc = __builtin_amdgcn_mfma_f32_16x16x32_bf16(a_hi[kh], b_lo, acc, 0, 0, 0);
    }
    const float bc = bias[c];
    #pragma unroll
    for (int e = 0; e < 4; ++e) {
        const int row = rb + g * 4 + e;
        const float val = acc[e] + bc;
        if      (m == 0) Qb[row * DM + c] = (__bf16)(val * 0.125f); // fold 1/sqrt(dk)
        else if (m == 1) Kb[row * DM + c] = (__bf16)val;
        else {
            const int local = row & 31;
            const int p = ((local & 15) >> 2) * 8 + (local >> 4) * 4 + (local & 3);
            Vs[((row >> 5) * 64 + c) * 32 + p] = (__bf16)val;
        }
    }
}

// ---------------------------------------------------------------------------
// One KV tile step: issue V(current)+K(next) loads, pin them with
// sched_barrier, then QK^T -> branchless mask/exp -> sigma-pack -> PV.
// All conditions are uniform selects or lane-local cndmask: NO branches.
// ---------------------------------------------------------------------------
__device__ __attribute__((always_inline)) inline void tile_step(
    int t, int ntiles, int qglob, int r, int g,
    const bfrag& qf0, const bfrag& qf1,
    const __bf16* __restrict__ Kb, const __bf16* __restrict__ Vs,
    bfrag (&kc)[4], bfrag (&kn)[4], f4 (&o)[4], float& ls)
{
    const int tn = t + 8;
    const int tc = (tn < ntiles) ? tn : (ntiles - 1);   // uniform clamp (SALU)
    const int tv = (t  < ntiles) ? t  : (ntiles - 1);
    bfrag vf[4];
    load_v(Vs, tv, r, g, vf);          // current tile V: used after QK+exp
    load_k(Kb, tc * 32, r, g, kn);     // next tile K: used next step
    __builtin_amdgcn_sched_barrier(0); // pin load issue before this tile's compute

    f4 s0 = {0,0,0,0}, s1 = {0,0,0,0};                  // S'[kv][q]: swapped
    s0 = __builtin_amdgcn_mfma_f32_16x16x32_bf16(kc[0], qf0, s0, 0, 0, 0);
    s0 = __builtin_amdgcn_mfma_f32_16x16x32_bf16(kc[1], qf1, s0, 0, 0, 0);
    s1 = __builtin_amdgcn_mfma_f32_16x16x32_bf16(kc[2], qf0, s1, 0, 0, 0);
    s1 = __builtin_amdgcn_mfma_f32_16x16x32_bf16(kc[3], qf1, s1, 0, 0, 0);

    const bool tin  = (t < ntiles);          // padded iterations contribute 0
    const bool tful = (t < ntiles - 1);      // non-diagonal tiles: no mask
    float p0[4], p1[4];
    #pragma unroll
    for (int e = 0; e < 4; ++e) {
        const int kv0 = t * 32 + g * 4 + e;
        const bool k0 = tin && (tful || (kv0      <= qglob));
        const bool k1 = tin && (tful || (kv0 + 16 <= qglob));
        p0[e] = k0 ? __expf(s0[e]) : 0.f;
        p1[e] = k1 ? __expf(s1[e]) : 0.f;
    }
    ls += (p0[0] + p0[1]) + (p0[2] + p0[3]) + (p1[0] + p1[1]) + (p1[2] + p1[3]);

    PW pu;                                   // sigma pack: slots 0-3 <- p0, 4-7 <- p1
    pu.w[0] = pack_bf16(p0[0], p0[1]);
    pu.w[1] = pack_bf16(p0[2], p0[3]);
    pu.w[2] = pack_bf16(p1[0], p1[1]);
    pu.w[3] = pack_bf16(p1[2], p1[3]);

    o[0] = __builtin_amdgcn_mfma_f32_16x16x32_bf16(pu.v, vf[0], o[0], 0, 0, 0);
    o[1] = __builtin_amdgcn_mfma_f32_16x16x32_bf16(pu.v, vf[1], o[1], 0, 0, 0);
    o[2] = __builtin_amdgcn_mfma_f32_16x16x32_bf16(pu.v, vf[2], o[2], 0, 0, 0);
    o[3] = __builtin_amdgcn_mfma_f32_16x16x32_bf16(pu.v, vf[3], o[3], 0, 0, 0);
}

// ---------------------------------------------------------------------------
// Kernel 2: flash attention. 512 blocks (one 16-row q-tile each; pairing
// b/511-b balances CUs under round-robin dispatch) x 8 waves; wave w takes
// KV tiles w, w+8, ... Ping-ponged K prefetch (kA/kB), branch-free body.
// No online max (scores bounded; exp fp32). Wave partials additive ->
// LDS combine epilogue -> direct normalized out.
// ---------------------------------------------------------------------------
__global__ __launch_bounds__(512, 4) void flash_attn(
    const __bf16* __restrict__ Qb, const __bf16* __restrict__ Kb,
    const __bf16* __restrict__ Vs, float* __restrict__ out)
{
    __shared__ float Olds[8][16][68];
    __shared__ float Ls[8][16];
    const int tid  = threadIdx.x;
    const int lane = tid & 63;
    const int wid  = tid >> 6;                  // 0..7
    const int b    = blockIdx.x;
    const int qt   = (b < 256) ? (511 - b) : (b - 256);  // pair big+small per CU
    const int qbase = qt * 16;
    const int g = lane >> 4;
    const int r = lane & 15;
    const int qglob = qbase + r;                // this lane's q-row

    const bfrag qf0 = *(const bfrag*)(Qb + qglob * DM + g * 8);
    const bfrag qf1 = *(const bfrag*)(Qb + qglob * DM + 32 + g * 8);

    f4 o[4] = {f4{0,0,0,0}, f4{0,0,0,0}, f4{0,0,0,0}, f4{0,0,0,0}};
    float ls = 0.f;

    const int ntiles = qt / 2 + 1;
    const int ws = wid;
    const int niter = (ws < ntiles) ? ((ntiles - ws + 7) >> 3) : 0;

    if (niter > 0) {
        bfrag kA[4], kB[4];
        load_k(Kb, ws * 32, r, g, kA);
        const int nstep = (niter + 1) & ~1;     // pad to even; extras masked to 0
        int t = ws;
        for (int it = 0; it < nstep; it += 2) {
            tile_step(t,     ntiles, qglob, r, g, qf0, qf1, Kb, Vs, kA, kB, o, ls);
            tile_step(t + 8, ntiles, qglob, r, g, qf0, qf1, Kb, Vs, kB, kA, o, ls);
            t += 16;
        }
    }

    // ls is partial row-sum for q=r across this wave's tiles; fold 4 lane-groups
    ls += __shfl_xor(ls, 16, 64);
    ls += __shfl_xor(ls, 32, 64);
    if (lane < 16) Ls[wid][r] = ls;
    #pragma unroll
    for (int dt = 0; dt < 4; ++dt)
        #pragma unroll
        for (int e = 0; e < 4; ++e)
            Olds[wid][g * 4 + e][dt * 16 + r] = o[dt][e];   // O[q][d]
    __syncthreads();

    // cross-wave combine -> normalized output
    for (int i = tid; i < 16 * 64; i += 512) {
        const int row = i >> 6, col = i & 63;
        float s = 0.f;
        #pragma unroll
        for (int w = 0; w < 8; ++w) s += Olds[w][row][col];
        const float l = ((Ls[0][row] + Ls[1][row]) + (Ls[2][row] + Ls[3][row]))
                      + ((Ls[4][row] + Ls[5][row]) + (Ls[6][row] + Ls[7][row]));
        out[(qbase + row) * DM + col] = s / l;
    }
}

extern "C" void kernel_launch(void* const* d_in, const int* in_sizes, int n_in,
                              void* d_out, int out_size, void* d_ws, size_t ws_size,
                              hipStream_t stream)
{
    (void)in_sizes; (void)n_in; (void)out_size; (void)ws_size;
    const float* x  = (const float*)d_in[0];
    const float* wq = (const float*)d_in[1];
    const float* bq = (const float*)d_in[2];
    const float* wk = (const float*)d_in[3];
    const float* bk = (const float*)d_in[4];
    const float* wv = (const float*)d_in[5];
    const float* bv = (const float*)d_in[6];
    float* out = (float*)d_out;

    __bf16* Qb = (__bf16*)d_ws;                       // [S][64] bf16, 1 MB
    __bf16* Kb = Qb + SEQ * DM;                       // [S][64] bf16, 1 MB
    __bf16* Vs = Kb + SEQ * DM;                       // [S/32][64][32] bf16, 1 MB

    qkv_proj<<<1536, 256, 0, stream>>>(x, wq, bq, wk, bk, wv, bv, Qb, Kb, Vs);
    flash_attn<<<512, 512, 0, stream>>>(Qb, Kb, Vs, out);
}

// Round 7
// 62.400 us; speedup vs baseline: 1.0179x; 1.0179x over previous
//
#include <hip/hip_runtime.h>

#define SEQ 8192
#define DM 64

typedef __bf16 bfrag __attribute__((ext_vector_type(8)));   // MFMA A/B operand
typedef float  f4    __attribute__((ext_vector_type(4)));   // MFMA C/D operand

union PW { int w[4]; bfrag v; };

__device__ inline int pack_bf16(float a, float b) {
    const __bf16 ba = (__bf16)a, bb = (__bf16)b;
    const unsigned short ua = __builtin_bit_cast(unsigned short, ba);
    const unsigned short ub = __builtin_bit_cast(unsigned short, bb);
    return (int)(((unsigned)ub << 16) | (unsigned)ua);
}

// split a float into bf16 hi + bf16 lo (residual) for near-fp32 MFMA matmul
__device__ inline void split8(const float* __restrict__ p, bfrag& hi, bfrag& lo) {
    #pragma unroll
    for (int e = 0; e < 8; ++e) {
        const float v = p[e];
        const __bf16 h = (__bf16)v;
        hi[e] = h;
        lo[e] = (__bf16)(v - (float)h);
    }
}

__device__ __attribute__((always_inline)) inline void load_k(
    const __bf16* __restrict__ Kb, int kvb, int r, int g, bfrag (&k)[4]) {
    k[0] = *(const bfrag*)(Kb + (kvb + r) * DM + g * 8);
    k[1] = *(const bfrag*)(Kb + (kvb + r) * DM + 32 + g * 8);
    k[2] = *(const bfrag*)(Kb + (kvb + 16 + r) * DM + g * 8);
    k[3] = *(const bfrag*)(Kb + (kvb + 16 + r) * DM + 32 + g * 8);
}

__device__ __attribute__((always_inline)) inline void load_v(
    const __bf16* __restrict__ Vs, int t, int r, int g, bfrag (&v)[4]) {
    const __bf16* vb = Vs + t * 2048 + r * 32 + g * 8;
    v[0] = *(const bfrag*)(vb);
    v[1] = *(const bfrag*)(vb + 512);
    v[2] = *(const bfrag*)(vb + 1024);
    v[3] = *(const bfrag*)(vb + 1536);
}

// ---------------------------------------------------------------------------
// Kernel 1 (MFMA): 3072 wave-tasks = (matrix m, 16-row tile, dt-half).
// 768 blocks x 4 waves. hi/lo bf16 split (~fp32 accuracy).
// q -> bf16 [S][64] (pre-scaled 1/8); k -> bf16 [S][64];
// v -> bf16 sigma-permuted tile-major Vs[S/32][64][32]:
//   row-local kv -> p = ((kv&15)>>2)*8 + (kv>>4)*4 + (kv&3)
// ---------------------------------------------------------------------------
__global__ __launch_bounds__(256) void qkv_proj(
    const float* __restrict__ x,
    const float* __restrict__ wq, const float* __restrict__ bq,
    const float* __restrict__ wk, const float* __restrict__ bk,
    const float* __restrict__ wv, const float* __restrict__ bv,
    __bf16* __restrict__ Qb, __bf16* __restrict__ Kb, __bf16* __restrict__ Vs)
{
    const int lane = threadIdx.x & 63;
    const int wid  = threadIdx.x >> 6;
    const int task = blockIdx.x * 4 + wid;      // 0..3071
    const int m    = task >> 10;                // 0..2
    const int rt   = (task >> 1) & 511;
    const int half = task & 1;
    const int rb   = rt << 4;                   // 16 rows
    const int g = lane >> 4, r = lane & 15;

    const float* w    = (m == 0) ? wq : (m == 1) ? wk : wv;
    const float* bias = (m == 0) ? bq : (m == 1) ? bk : bv;

    bfrag a_hi[2], a_lo[2];
    #pragma unroll
    for (int kh = 0; kh < 2; ++kh)
        split8(x + (rb + r) * DM + kh * 32 + g * 8, a_hi[kh], a_lo[kh]);

    #pragma unroll
    for (int di = 0; di < 2; ++di) {
        const int dt = half * 2 + di;
        const int c = dt * 16 + r;              // output feature
        f4 acc = {0.f, 0.f, 0.f, 0.f};
        #pragma unroll
        for (int kh = 0; kh < 2; ++kh) {
            bfrag b_hi, b_lo;
            split8(w + c * DM + kh * 32 + g * 8, b_hi, b_lo);
            acc = __builtin_amdgcn_mfma_f32_16x16x32_bf16(a_hi[kh], b_hi, acc, 0, 0, 0);
            acc = __builtin_amdgcn_mfma_f32_16x16x32_bf16(a_lo[kh], b_hi, acc, 0, 0, 0);
            acc = __builtin_amdgcn_mfma_f32_16x16x32_bf16(a_hi[kh], b_lo, acc, 0, 0, 0);
        }
        const float bc = bias[c];
        #pragma unroll
        for (int e = 0; e < 4; ++e) {
            const int row = rb + g * 4 + e;
            const float val = acc[e] + bc;
            if      (m == 0) Qb[row * DM + c] = (__bf16)(val * 0.125f); // fold 1/sqrt(dk)
            else if (m == 1) Kb[row * DM + c] = (__bf16)val;
            else {
                const int local = row & 31;
                const int p = ((local & 15) >> 2) * 8 + (local >> 4) * 4 + (local & 3);
                Vs[((row >> 5) * 64 + c) * 32 + p] = (__bf16)val;
            }
        }
    }
}

// ---------------------------------------------------------------------------
// One KV tile step: prefetch K(t+8),V(t+8) into the "next" ping-pong regs,
// then compute tile t from the "current" regs: QK^T -> branchless mask/exp
// -> sigma-pack -> PV. No branches, no cross-lane ops, no LDS.
// ---------------------------------------------------------------------------
__device__ __attribute__((always_inline)) inline void tile_step(
    int t, int ntiles, int qglob, int r, int g,
    const bfrag& qf0, const bfrag& qf1,
    const __bf16* __restrict__ Kb, const __bf16* __restrict__ Vs,
    bfrag (&kc)[4], bfrag (&kn)[4], bfrag (&vc)[4], bfrag (&vn)[4],
    f4 (&o)[4], float& ls)
{
    const int tn = (t + 8 < ntiles) ? (t + 8) : (ntiles - 1);   // uniform clamp
    load_k(Kb, tn * 32, r, g, kn);      // next-step K: full step of slack
    load_v(Vs, tn, r, g, vn);           // next-step V: full step of slack

    f4 s0 = {0,0,0,0}, s1 = {0,0,0,0};                  // S'[kv][q]: swapped
    s0 = __builtin_amdgcn_mfma_f32_16x16x32_bf16(kc[0], qf0, s0, 0, 0, 0);
    s0 = __builtin_amdgcn_mfma_f32_16x16x32_bf16(kc[1], qf1, s0, 0, 0, 0);
    s1 = __builtin_amdgcn_mfma_f32_16x16x32_bf16(kc[2], qf0, s1, 0, 0, 0);
    s1 = __builtin_amdgcn_mfma_f32_16x16x32_bf16(kc[3], qf1, s1, 0, 0, 0);

    const bool tin  = (t < ntiles);          // padded iterations contribute 0
    const bool tful = (t < ntiles - 1);      // non-diagonal tiles: no mask
    float p0[4], p1[4];
    #pragma unroll
    for (int e = 0; e < 4; ++e) {
        const int kv0 = t * 32 + g * 4 + e;
        const bool k0 = tin && (tful || (kv0      <= qglob));
        const bool k1 = tin && (tful || (kv0 + 16 <= qglob));
        p0[e] = k0 ? __expf(s0[e]) : 0.f;
        p1[e] = k1 ? __expf(s1[e]) : 0.f;
    }
    ls += (p0[0] + p0[1]) + (p0[2] + p0[3]) + (p1[0] + p1[1]) + (p1[2] + p1[3]);

    PW pu;                                   // sigma pack: slots 0-3 <- p0, 4-7 <- p1
    pu.w[0] = pack_bf16(p0[0], p0[1]);
    pu.w[1] = pack_bf16(p0[2], p0[3]);
    pu.w[2] = pack_bf16(p1[0], p1[1]);
    pu.w[3] = pack_bf16(p1[2], p1[3]);

    o[0] = __builtin_amdgcn_mfma_f32_16x16x32_bf16(pu.v, vc[0], o[0], 0, 0, 0);
    o[1] = __builtin_amdgcn_mfma_f32_16x16x32_bf16(pu.v, vc[1], o[1], 0, 0, 0);
    o[2] = __builtin_amdgcn_mfma_f32_16x16x32_bf16(pu.v, vc[2], o[2], 0, 0, 0);
    o[3] = __builtin_amdgcn_mfma_f32_16x16x32_bf16(pu.v, vc[3], o[3], 0, 0, 0);
}

// ---------------------------------------------------------------------------
// Kernel 2: flash attention. 512 blocks (one 16-row q-tile; pairing b/511-b
// balances CUs) x 8 waves; wave w takes KV tiles w, w+8, ...
// Residency is grid-limited to 2 blocks/CU = 4 waves/EU, so we DECLARE
// exactly that via amdgpu_waves_per_eu(4,4): register budget 128 -> the
// scheduler keeps both K and V ping-pong prefetch buffers live a full
// step ahead instead of strangling ILP for unreachable occupancy.
// ---------------------------------------------------------------------------
__global__ __launch_bounds__(512)
__attribute__((amdgpu_waves_per_eu(4, 4)))
void flash_attn(
    const __bf16* __restrict__ Qb, const __bf16* __restrict__ Kb,
    const __bf16* __restrict__ Vs, float* __restrict__ out)
{
    __shared__ float Olds[8][16][68];
    __shared__ float Ls[8][16];
    const int tid  = threadIdx.x;
    const int lane = tid & 63;
    const int wid  = tid >> 6;                  // 0..7
    const int b    = blockIdx.x;
    const int qt   = (b < 256) ? (511 - b) : (b - 256);  // pair big+small per CU
    const int qbase = qt * 16;
    const int g = lane >> 4;
    const int r = lane & 15;
    const int qglob = qbase + r;                // this lane's q-row

    const bfrag qf0 = *(const bfrag*)(Qb + qglob * DM + g * 8);
    const bfrag qf1 = *(const bfrag*)(Qb + qglob * DM + 32 + g * 8);

    f4 o[4] = {f4{0,0,0,0}, f4{0,0,0,0}, f4{0,0,0,0}, f4{0,0,0,0}};
    float ls = 0.f;

    const int ntiles = qt / 2 + 1;
    const int ws = wid;
    const int niter = (ws < ntiles) ? ((ntiles - ws + 7) >> 3) : 0;

    if (niter > 0) {
        bfrag kA[4], kB[4], vA[4], vB[4];
        load_k(Kb, ws * 32, r, g, kA);
        load_v(Vs, ws, r, g, vA);
        const int nstep = (niter + 1) & ~1;     // pad to even; extras masked to 0
        int t = ws;
        for (int it = 0; it < nstep; it += 2) {
            tile_step(t,     ntiles, qglob, r, g, qf0, qf1, Kb, Vs, kA, kB, vA, vB, o, ls);
            tile_step(t + 8, ntiles, qglob, r, g, qf0, qf1, Kb, Vs, kB, kA, vB, vA, o, ls);
            t += 16;
        }
    }

    // ls is partial row-sum for q=r across this wave's tiles; fold 4 lane-groups
    ls += __shfl_xor(ls, 16, 64);
    ls += __shfl_xor(ls, 32, 64);
    if (lane < 16) Ls[wid][r] = ls;
    #pragma unroll
    for (int dt = 0; dt < 4; ++dt)
        #pragma unroll
        for (int e = 0; e < 4; ++e)
            Olds[wid][g * 4 + e][dt * 16 + r] = o[dt][e];   // O[q][d]
    __syncthreads();

    // cross-wave combine -> normalized output
    for (int i = tid; i < 16 * 64; i += 512) {
        const int row = i >> 6, col = i & 63;
        float s = 0.f;
        #pragma unroll
        for (int w = 0; w < 8; ++w) s += Olds[w][row][col];
        const float l = ((Ls[0][row] + Ls[1][row]) + (Ls[2][row] + Ls[3][row]))
                      + ((Ls[4][row] + Ls[5][row]) + (Ls[6][row] + Ls[7][row]));
        out[(qbase + row) * DM + col] = s / l;
    }
}

extern "C" void kernel_launch(void* const* d_in, const int* in_sizes, int n_in,
                              void* d_out, int out_size, void* d_ws, size_t ws_size,
                              hipStream_t stream)
{
    (void)in_sizes; (void)n_in; (void)out_size; (void)ws_size;
    const float* x  = (const float*)d_in[0];
    const float* wq = (const float*)d_in[1];
    const float* bq = (const float*)d_in[2];
    const float* wk = (const float*)d_in[3];
    const float* bk = (const float*)d_in[4];
    const float* wv = (const float*)d_in[5];
    const float* bv = (const float*)d_in[6];
    float* out = (float*)d_out;

    __bf16* Qb = (__bf16*)d_ws;                       // [S][64] bf16, 1 MB
    __bf16* Kb = Qb + SEQ * DM;                       // [S][64] bf16, 1 MB
    __bf16* Vs = Kb + SEQ * DM;                       // [S/32][64][32] bf16, 1 MB

    qkv_proj<<<768, 256, 0, stream>>>(x, wq, bq, wk, bk, wv, bv, Qb, Kb, Vs);
    flash_attn<<<512, 512, 0, stream>>>(Qb, Kb, Vs, out);
}

// Round 9
// 52.406 us; speedup vs baseline: 1.2120x; 1.1907x over previous
//
#include <hip/hip_runtime.h>

#define SEQ 8192
#define DM 64

typedef __bf16 bfrag __attribute__((ext_vector_type(8)));   // MFMA A/B operand
typedef __bf16 b4v   __attribute__((ext_vector_type(4)));   // 8-byte bf16 pack
typedef float  f4    __attribute__((ext_vector_type(4)));   // MFMA C/D operand

union PW { int w[4]; bfrag v; };

#define GLOAD16(gsrc, ldst)                                                \
    __builtin_amdgcn_global_load_lds(                                      \
        (const __attribute__((address_space(1))) unsigned int*)(gsrc),     \
        (__attribute__((address_space(3))) unsigned int*)(ldst), 16, 0, 0)

__device__ inline int pack_bf16(float a, float b) {
    const __bf16 ba = (__bf16)a, bb = (__bf16)b;
    const unsigned short ua = __builtin_bit_cast(unsigned short, ba);
    const unsigned short ub = __builtin_bit_cast(unsigned short, bb);
    return (int)(((unsigned)ub << 16) | (unsigned)ua);
}

// split f32 x8 into bf16 hi + bf16 lo (residual) for near-fp32 MFMA matmul
__device__ inline void split8(const float* __restrict__ p, bfrag& hi, bfrag& lo) {
    #pragma unroll
    for (int e = 0; e < 8; ++e) {
        const float v = p[e];
        const __bf16 h = (__bf16)v;
        hi[e] = h;
        lo[e] = (__bf16)(v - (float)h);
    }
}

// ---------------------------------------------------------------------------
// Kernel 1 (MFMA): 3072 wave-tasks = (matrix m, 16-row x-tile, dt-half).
// 768 blocks x 4 waves. hi/lo bf16 split (~fp32 accuracy).
// Q/K use mfma(W, X): D[row=c-feature][col=x-row] -> per lane 4 CONSECUTIVE
//   output features -> one packed 8B store per dt. q pre-scaled by 1/8.
// V uses mfma(X, W): D[row=x-row(kv)][col=d] -> 4 consecutive sigma slots
//   (p = P0+e) -> one packed 8B store per dt into Vs[S/32][64][32].
//   sigma: slot = ((L&15)>>2)*8 + (L>>4)*4 + (L&3), L = kv row mod 32.
// ---------------------------------------------------------------------------
__global__ __launch_bounds__(256) void qkv_proj(
    const float* __restrict__ x,
    const float* __restrict__ wq, const float* __restrict__ bq,
    const float* __restrict__ wk, const float* __restrict__ bk,
    const float* __restrict__ wv, const float* __restrict__ bv,
    __bf16* __restrict__ Qb, __bf16* __restrict__ Kb, __bf16* __restrict__ Vs)
{
    const int lane = threadIdx.x & 63;
    const int wid  = threadIdx.x >> 6;
    const int task = blockIdx.x * 4 + wid;      // 0..3071
    const int m    = task >> 10;                // 0..2
    const int rest = task & 1023;
    const int rt   = rest >> 1;                 // 0..511
    const int half = rest & 1;
    const int rb   = rt << 4;                   // 16 x-rows
    const int g = lane >> 4, r = lane & 15;

    const float* w    = (m == 0) ? wq : (m == 1) ? wk : wv;
    const float* bias = (m == 0) ? bq : (m == 1) ? bk : bv;

    bfrag xhi[2], xlo[2];                       // X rows rb+r (A or B frag, same bits)
    #pragma unroll
    for (int kh = 0; kh < 2; ++kh)
        split8(x + (rb + r) * DM + kh * 32 + g * 8, xhi[kh], xlo[kh]);

    #pragma unroll
    for (int di = 0; di < 2; ++di) {
        const int dt = half * 2 + di;
        bfrag whi[2], wlo[2];                   // W rows dt*16+r
        #pragma unroll
        for (int kh = 0; kh < 2; ++kh)
            split8(w + (dt * 16 + r) * DM + kh * 32 + g * 8, whi[kh], wlo[kh]);

        f4 acc = {0.f, 0.f, 0.f, 0.f};
        if (m < 2) {                            // Q/K: mfma(W, X)
            #pragma unroll
            for (int kh = 0; kh < 2; ++kh) {
                acc = __builtin_amdgcn_mfma_f32_16x16x32_bf16(whi[kh], xhi[kh], acc, 0, 0, 0);
                acc = __builtin_amdgcn_mfma_f32_16x16x32_bf16(wlo[kh], xhi[kh], acc, 0, 0, 0);
                acc = __builtin_amdgcn_mfma_f32_16x16x32_bf16(whi[kh], xlo[kh], acc, 0, 0, 0);
            }
            const int c0 = dt * 16 + g * 4;     // 4 consecutive output features
            const float4 b4 = *(const float4*)(bias + c0);
            const float sc = (m == 0) ? 0.125f : 1.0f;   // fold 1/sqrt(dk) into Q
            b4v pv;
            pv[0] = (__bf16)((acc[0] + b4.x) * sc);
            pv[1] = (__bf16)((acc[1] + b4.y) * sc);
            pv[2] = (__bf16)((acc[2] + b4.z) * sc);
            pv[3] = (__bf16)((acc[3] + b4.w) * sc);
            __bf16* dst = (m == 0) ? Qb : Kb;
            *(b4v*)(dst + (rb + r) * DM + c0) = pv;
        } else {                                // V: mfma(X, W)
            #pragma unroll
            for (int kh = 0; kh < 2; ++kh) {
                acc = __builtin_amdgcn_mfma_f32_16x16x32_bf16(xhi[kh], whi[kh], acc, 0, 0, 0);
                acc = __builtin_amdgcn_mfma_f32_16x16x32_bf16(xlo[kh], whi[kh], acc, 0, 0, 0);
                acc = __builtin_amdgcn_mfma_f32_16x16x32_bf16(xhi[kh], wlo[kh], acc, 0, 0, 0);
            }
            const int d  = dt * 16 + r;
            const float bd = bias[d];
            const int L0 = (rb & 31) + g * 4;   // kv rows rb+g*4+e, e=0..3
            const int P0 = ((L0 & 15) >> 2) * 8 + (L0 >> 4) * 4;  // +e consecutive
            b4v pv;
            pv[0] = (__bf16)(acc[0] + bd);
            pv[1] = (__bf16)(acc[1] + bd);
            pv[2] = (__bf16)(acc[2] + bd);
            pv[3] = (__bf16)(acc[3] + bd);
            *(b4v*)(Vs + (rb >> 5) * 2048 + d * 32 + P0) = pv;
        }
    }
}

// ---------------------------------------------------------------------------
// Kernel 2: flash attention partials.
// Grid 512 = (qt 0..255: 32 q-rows) x (g 0..1: kv slice), balanced pairing.
// Block = 4 waves. Per super-step s: cooperatively stage kv tiles
// j = s*8 + 4g + {0..3} (128 rows: K 16 KB + V 16 KB) via global_load_lds
// (async, no dest regs -> loads overlap; __syncthreads drains).
// K staged with XOR-source-swizzle (chunk ^= row&7) -> conflict-free b128
// reads; V with chunk ^= row&3 (4-way residual, cheap).
// Wave w computes tile j0+w against BOTH q-subtiles (Q-reuse=2).
// Swapped QK^T + sigma V (verified rounds 5-7). No online max.
// ---------------------------------------------------------------------------
__global__ __launch_bounds__(256)
__attribute__((amdgpu_waves_per_eu(2)))
void flash_attn(
    const __bf16* __restrict__ Qb, const __bf16* __restrict__ Kb,
    const __bf16* __restrict__ Vs,
    float* __restrict__ Opart, float* __restrict__ Lpart)
{
    __shared__ __align__(16) unsigned char smem[36864];
    unsigned char* Ksm = smem;               // 16 KB staged K (128 rows x 128 B)
    unsigned char* Vsm = smem + 16384;       // 16 KB staged V (4 tiles x 4 KB)

    const int tid  = threadIdx.x;
    const int lane = tid & 63;
    const int wid  = tid >> 6;               // 0..3
    const int b    = blockIdx.x;
    const int qt   = (b < 256) ? (255 - (b >> 1)) : ((b - 256) >> 1);
    const int g2   = b & 1;                  // kv slice
    const int gq   = lane >> 4;              // 0..3
    const int r    = lane & 15;

    // Q fragments for both 16-row subtiles (B-operand; col=r -> q-row)
    bfrag qf[2][2];
    #pragma unroll
    for (int sub = 0; sub < 2; ++sub)
        #pragma unroll
        for (int kh = 0; kh < 2; ++kh)
            qf[sub][kh] = *(const bfrag*)(Qb + (qt * 32 + sub * 16 + r) * DM + kh * 32 + gq * 8);

    f4 o[2][4] = {};
    float ls[2] = {0.f, 0.f};

    const int nsteps = (qt >= 4 * g2) ? (((qt - 4 * g2) >> 3) + 1) : 0;

    const int klrow = lane >> 3, kc = lane & 7;          // K staging lane map
    const int kcg   = kc ^ (klrow & 7);
    const int vlrow = lane >> 2, vc = lane & 3;          // V staging lane map
    const int vcg   = vc ^ (vlrow & 3);
    const char* Kbb = (const char*)Kb;
    const char* Vbb = (const char*)Vs;

    for (int s = 0; s < nsteps; ++s) {
        const int j0 = s * 8 + g2 * 4;       // first kv tile this step
        const long long base = (long long)j0 * 4096;
        // ---- cooperative staging: 8 async global_load_lds per thread ----
        #pragma unroll
        for (int jr = 0; jr < 4; ++jr) {
            const int st = jr * 4 + wid;     // 1-KB stripe 0..15
            GLOAD16(Kbb + base + st * 1024 + klrow * 128 + kcg * 16, Ksm + st * 1024);
        }
        #pragma unroll
        for (int jr = 0; jr < 4; ++jr) {
            const int st = jr * 4 + wid;
            GLOAD16(Vbb + base + st * 1024 + vlrow * 64 + vcg * 16, Vsm + st * 1024);
        }
        __syncthreads();                     // drains vmcnt -> staged data ready

        // ---- compute: wave wid's kv tile j, vs both q-subtiles ----
        const int j = j0 + wid;
        const unsigned char* Kr = Ksm + wid * 4096;
        const unsigned char* Vr = Vsm + wid * 4096;
        const int r7 = r & 7, r3 = r & 3;
        const bfrag kf0 = *(const bfrag*)(Kr + r * 128        + ((gq ^ r7) << 4));
        const bfrag kf1 = *(const bfrag*)(Kr + r * 128        + (((4 | gq) ^ r7) << 4));
        const bfrag kf2 = *(const bfrag*)(Kr + (16 + r) * 128 + ((gq ^ r7) << 4));
        const bfrag kf3 = *(const bfrag*)(Kr + (16 + r) * 128 + (((4 | gq) ^ r7) << 4));
        bfrag vf[4];
        #pragma unroll
        for (int dt = 0; dt < 4; ++dt)
            vf[dt] = *(const bfrag*)(Vr + (dt * 16 + r) * 64 + ((gq ^ r3) << 4));

        f4 s00 = {}, s01 = {}, s10 = {}, s11 = {};   // [sub][kv-half]
        s00 = __builtin_amdgcn_mfma_f32_16x16x32_bf16(kf0, qf[0][0], s00, 0, 0, 0);
        s00 = __builtin_amdgcn_mfma_f32_16x16x32_bf16(kf1, qf[0][1], s00, 0, 0, 0);
        s01 = __builtin_amdgcn_mfma_f32_16x16x32_bf16(kf2, qf[0][0], s01, 0, 0, 0);
        s01 = __builtin_amdgcn_mfma_f32_16x16x32_bf16(kf3, qf[0][1], s01, 0, 0, 0);
        s10 = __builtin_amdgcn_mfma_f32_16x16x32_bf16(kf0, qf[1][0], s10, 0, 0, 0);
        s10 = __builtin_amdgcn_mfma_f32_16x16x32_bf16(kf1, qf[1][1], s10, 0, 0, 0);
        s11 = __builtin_amdgcn_mfma_f32_16x16x32_bf16(kf2, qf[1][0], s11, 0, 0, 0);
        s11 = __builtin_amdgcn_mfma_f32_16x16x32_bf16(kf3, qf[1][1], s11, 0, 0, 0);

        const bool valid = (j <= qt);
        const bool ndiag = (j < qt);
        float p00[4], p01[4], p10[4], p11[4];
        #pragma unroll
        for (int e = 0; e < 4; ++e) {
            const bool kle = (gq * 4 + e <= r);
            p00[e] = (valid && (ndiag || kle)) ? __expf(s00[e]) : 0.f;  // sub0, kv 0..15
            p01[e] = (valid && ndiag)          ? __expf(s01[e]) : 0.f;  // sub0, kv 16..31
            p10[e] = valid                     ? __expf(s10[e]) : 0.f;  // sub1, kv 0..15
            p11[e] = (valid && (ndiag || kle)) ? __expf(s11[e]) : 0.f;  // sub1, kv 16..31
        }
        ls[0] += (p00[0] + p00[1]) + (p00[2] + p00[3]) + (p01[0] + p01[1]) + (p01[2] + p01[3]);
        ls[1] += (p10[0] + p10[1]) + (p10[2] + p10[3]) + (p11[0] + p11[1]) + (p11[2] + p11[3]);

        PW pu0, pu1;                         // sigma pack: slots 0-3 <- h0, 4-7 <- h1
        pu0.w[0] = pack_bf16(p00[0], p00[1]); pu0.w[1] = pack_bf16(p00[2], p00[3]);
        pu0.w[2] = pack_bf16(p01[0], p01[1]); pu0.w[3] = pack_bf16(p01[2], p01[3]);
        pu1.w[0] = pack_bf16(p10[0], p10[1]); pu1.w[1] = pack_bf16(p10[2], p10[3]);
        pu1.w[2] = pack_bf16(p11[0], p11[1]); pu1.w[3] = pack_bf16(p11[2], p11[3]);

        #pragma unroll
        for (int dt = 0; dt < 4; ++dt) {
            o[0][dt] = __builtin_amdgcn_mfma_f32_16x16x32_bf16(pu0.v, vf[dt], o[0][dt], 0, 0, 0);
            o[1][dt] = __builtin_amdgcn_mfma_f32_16x16x32_bf16(pu1.v, vf[dt], o[1][dt], 0, 0, 0);
        }
        __syncthreads();                     // everyone done reading before restage
    }

    // ---- epilogue: combine 4 waves' kv-slice partials (reuse smem) ----
    float* Ol  = (float*)smem;               // [4][32][68]
    float* Lsm = (float*)(smem + 34816);     // [4][32]
    #pragma unroll
    for (int sub = 0; sub < 2; ++sub) {
        ls[sub] += __shfl_xor(ls[sub], 16, 64);
        ls[sub] += __shfl_xor(ls[sub], 32, 64);
        if (lane < 16) Lsm[wid * 32 + sub * 16 + r] = ls[sub];
        #pragma unroll
        for (int dt = 0; dt < 4; ++dt)
            #pragma unroll
            for (int e = 0; e < 4; ++e)
                Ol[(wid * 32 + sub * 16 + gq * 4 + e) * 68 + dt * 16 + r] = o[sub][dt][e];
    }
    __syncthreads();

    for (int i = tid; i < 32 * 64; i += 256) {
        const int row = i >> 6, col = i & 63;
        const float sum = Ol[(row) * 68 + col] + Ol[(32 + row) * 68 + col]
                        + Ol[(64 + row) * 68 + col] + Ol[(96 + row) * 68 + col];
        Opart[((long long)g2 * SEQ + qt * 32 + row) * DM + col] = sum;
    }
    if (tid < 32) {
        const float l = Lsm[tid] + Lsm[32 + tid] + Lsm[64 + tid] + Lsm[96 + tid];
        Lpart[g2 * SEQ + qt * 32 + tid] = l;
    }
}

// ---------------------------------------------------------------------------
// Kernel 3: out = (O0+O1) / (L0+L1)
// ---------------------------------------------------------------------------
__global__ __launch_bounds__(256) void normalize(
    const float* __restrict__ Opart, const float* __restrict__ Lpart,
    float* __restrict__ out)
{
    const int i = blockIdx.x * 256 + threadIdx.x;     // f4 index
    const f4* O0 = (const f4*)Opart;
    const f4* O1 = O0 + (SEQ * DM / 4);
    const int row = i >> 4;
    const f4 a = O0[i], b2 = O1[i];
    const float inv = 1.0f / (Lpart[row] + Lpart[SEQ + row]);
    f4 res;
    #pragma unroll
    for (int e = 0; e < 4; ++e) res[e] = (a[e] + b2[e]) * inv;
    ((f4*)out)[i] = res;
}

extern "C" void kernel_launch(void* const* d_in, const int* in_sizes, int n_in,
                              void* d_out, int out_size, void* d_ws, size_t ws_size,
                              hipStream_t stream)
{
    (void)in_sizes; (void)n_in; (void)out_size; (void)ws_size;
    const float* x  = (const float*)d_in[0];
    const float* wq = (const float*)d_in[1];
    const float* bq = (const float*)d_in[2];
    const float* wk = (const float*)d_in[3];
    const float* bk = (const float*)d_in[4];
    const float* wv = (const float*)d_in[5];
    const float* bv = (const float*)d_in[6];
    float* out = (float*)d_out;

    __bf16* Qb = (__bf16*)d_ws;                       // [S][64] bf16, 1 MB
    __bf16* Kb = Qb + SEQ * DM;                       // [S][64] bf16, 1 MB
    __bf16* Vs = Kb + SEQ * DM;                       // [S/32][64][32] bf16, 1 MB
    float*  Opart = (float*)(Vs + SEQ * DM);          // [2][S][64] f32, 4 MB
    float*  Lpart = Opart + 2 * SEQ * DM;             // [2][S] f32, 64 KB

    qkv_proj<<<768, 256, 0, stream>>>(x, wq, bq, wk, bk, wv, bv, Qb, Kb, Vs);
    flash_attn<<<512, 256, 0, stream>>>(Qb, Kb, Vs, Opart, Lpart);
    normalize<<<SEQ * DM / 4 / 256, 256, 0, stream>>>(Opart, Lpart, out);
}

// Round 10
// 40.905 us; speedup vs baseline: 1.5528x; 1.2811x over previous
//
#include <hip/hip_runtime.h>

#define SEQ 8192
#define DM 64

typedef __bf16 bfrag __attribute__((ext_vector_type(8)));   // MFMA A/B operand
typedef __bf16 b4v   __attribute__((ext_vector_type(4)));   // 8-byte bf16 pack
typedef float  f4    __attribute__((ext_vector_type(4)));   // MFMA C/D operand

union PW { int w[4]; bfrag v; };

#define GLOAD16(gsrc, ldst)                                                \
    __builtin_amdgcn_global_load_lds(                                      \
        (const __attribute__((address_space(1))) unsigned int*)(gsrc),     \
        (__attribute__((address_space(3))) unsigned int*)(ldst), 16, 0, 0)

__device__ inline int pack_bf16(float a, float b) {
    const __bf16 ba = (__bf16)a, bb = (__bf16)b;
    const unsigned short ua = __builtin_bit_cast(unsigned short, ba);
    const unsigned short ub = __builtin_bit_cast(unsigned short, bb);
    return (int)(((unsigned)ub << 16) | (unsigned)ua);
}

// split f32 x8 into bf16 hi + bf16 lo (residual) for near-fp32 MFMA matmul
__device__ inline void split8(const float* __restrict__ p, bfrag& hi, bfrag& lo) {
    #pragma unroll
    for (int e = 0; e < 8; ++e) {
        const float v = p[e];
        const __bf16 h = (__bf16)v;
        hi[e] = h;
        lo[e] = (__bf16)(v - (float)h);
    }
}

// ---------------------------------------------------------------------------
// Kernel 1 (MFMA): 2048 wave-tasks = (16-row x-tile rt, dt). 512 blocks x 4
// waves. Each wave splits x once, then does Q, K, V sequentially (ILP).
// hi/lo bf16 split (~fp32). Same verified MFMA math as round 9; only the
// K/V STORE ADDRESSES changed, to tile-major lane-linear layouts:
//  Ksig: tile t (32 kv rows x 64 feat): addr16B = t*4096B + b2*1024 +
//        (ch&3)*256 + (row&15)*16, b2 = (row>=16)*2 + (ch>=4), ch = feat/8.
//  Vsig: addr16B = t*4096B + dtv*1024 + gq*256 + rv*16  for (d = dtv*16+rv,
//        sigma-slot group gq); slot content identical to round 9's sigma.
//  -> flash reads become uniform_base + lane*16 (conflict-free) and staging
//     is a pure linear copy.
// ---------------------------------------------------------------------------
__global__ __launch_bounds__(256) void qkv_proj(
    const float* __restrict__ x,
    const float* __restrict__ wq, const float* __restrict__ bq,
    const float* __restrict__ wk, const float* __restrict__ bk,
    const float* __restrict__ wv, const float* __restrict__ bv,
    __bf16* __restrict__ Qb, __bf16* __restrict__ Ks, __bf16* __restrict__ Vg)
{
    const int lane = threadIdx.x & 63;
    const int wid  = threadIdx.x >> 6;
    const int task = blockIdx.x * 4 + wid;      // 0..2047
    const int rt   = task >> 2;                 // 0..511
    const int dt   = task & 3;                  // 0..3
    const int rb   = rt << 4;                   // 16 x-rows
    const int g = lane >> 4, r = lane & 15;

    bfrag xhi[2], xlo[2];                       // X rows rb+r
    #pragma unroll
    for (int kh = 0; kh < 2; ++kh)
        split8(x + (rb + r) * DM + kh * 32 + g * 8, xhi[kh], xlo[kh]);

    // ---- Q (m=0) and K (m=1): mfma(W, X) -> D[feat][x-row] ----
    #pragma unroll
    for (int m = 0; m < 2; ++m) {
        const float* w    = m ? wk : wq;
        const float* bias = m ? bk : bq;
        bfrag whi[2], wlo[2];
        #pragma unroll
        for (int kh = 0; kh < 2; ++kh)
            split8(w + (dt * 16 + r) * DM + kh * 32 + g * 8, whi[kh], wlo[kh]);
        f4 acc = {0.f, 0.f, 0.f, 0.f};
        #pragma unroll
        for (int kh = 0; kh < 2; ++kh) {
            acc = __builtin_amdgcn_mfma_f32_16x16x32_bf16(whi[kh], xhi[kh], acc, 0, 0, 0);
            acc = __builtin_amdgcn_mfma_f32_16x16x32_bf16(wlo[kh], xhi[kh], acc, 0, 0, 0);
            acc = __builtin_amdgcn_mfma_f32_16x16x32_bf16(whi[kh], xlo[kh], acc, 0, 0, 0);
        }
        const int c0 = dt * 16 + g * 4;         // 4 consecutive features
        const float4 b4 = *(const float4*)(bias + c0);
        const float sc = (m == 0) ? 0.125f : 1.0f;   // fold 1/sqrt(dk) into Q
        b4v pv;
        pv[0] = (__bf16)((acc[0] + b4.x) * sc);
        pv[1] = (__bf16)((acc[1] + b4.y) * sc);
        pv[2] = (__bf16)((acc[2] + b4.z) * sc);
        pv[3] = (__bf16)((acc[3] + b4.w) * sc);
        if (m == 0) {
            *(b4v*)(Qb + (rb + r) * DM + c0) = pv;
        } else {
            const int row = rb + r, t = row >> 5, row32 = row & 31;
            const int ch  = dt * 2 + (g >> 1);
            const int b2  = ((row32 >> 4) << 1) | (ch >> 2);
            *(b4v*)(Ks + t * 2048 + b2 * 512 + (ch & 3) * 128
                       + (row32 & 15) * 8 + (g & 1) * 4) = pv;
        }
    }

    // ---- V (m=2): mfma(X, W) -> D[x-row(kv)][feat] ----
    {
        bfrag whi[2], wlo[2];
        #pragma unroll
        for (int kh = 0; kh < 2; ++kh)
            split8(wv + (dt * 16 + r) * DM + kh * 32 + g * 8, whi[kh], wlo[kh]);
        f4 acc = {0.f, 0.f, 0.f, 0.f};
        #pragma unroll
        for (int kh = 0; kh < 2; ++kh) {
            acc = __builtin_amdgcn_mfma_f32_16x16x32_bf16(xhi[kh], whi[kh], acc, 0, 0, 0);
            acc = __builtin_amdgcn_mfma_f32_16x16x32_bf16(xlo[kh], whi[kh], acc, 0, 0, 0);
            acc = __builtin_amdgcn_mfma_f32_16x16x32_bf16(xhi[kh], wlo[kh], acc, 0, 0, 0);
        }
        const int d  = dt * 16 + r;
        const float bd = bv[d];
        const int L0 = (rb & 31) + g * 4;       // kv rows rb + g*4 + e
        const int P0 = ((L0 & 15) >> 2) * 8 + (L0 >> 4) * 4;  // sigma slot base
        const int t  = rb >> 5;
        b4v pv;
        pv[0] = (__bf16)(acc[0] + bd);
        pv[1] = (__bf16)(acc[1] + bd);
        pv[2] = (__bf16)(acc[2] + bd);
        pv[3] = (__bf16)(acc[3] + bd);
        *(b4v*)(Vg + t * 2048 + (d >> 4) * 512 + (P0 >> 3) * 128
                   + (d & 15) * 8 + (P0 & 7)) = pv;
    }
}

// ---------------------------------------------------------------------------
// Kernel 2: flash attention partials, double-buffered LDS staging.
// Grid 512 = (qt 0..255: 32 q-rows) x (g2 0..1 kv slice), balanced pairing.
// Per step: STAGE(next -> buf^1) issued FIRST (16 linear global_load_lds,
// latency hides under compute), then compute tiles of buf, one barrier.
// All LDS frag reads are uniform_base + lane*16 -> conflict-free b128.
// Swapped QK^T + sigma PV, no online max (verified rounds 5-9).
// ---------------------------------------------------------------------------
__global__ __launch_bounds__(256)
__attribute__((amdgpu_waves_per_eu(2)))
void flash_attn(
    const __bf16* __restrict__ Qb, const __bf16* __restrict__ Ks,
    const __bf16* __restrict__ Vg,
    float* __restrict__ Opart, float* __restrict__ Lpart)
{
    __shared__ __align__(16) unsigned char smem[2][32768];  // [buf][K 16K | V 16K]

    const int tid  = threadIdx.x;
    const int lane = tid & 63;
    const int wid  = tid >> 6;               // 0..3
    const int b    = blockIdx.x;
    const int qt   = (b < 256) ? (255 - (b >> 1)) : ((b - 256) >> 1);
    const int g2   = b & 1;                  // kv slice
    const int gq   = lane >> 4;              // 0..3
    const int r    = lane & 15;

    // Q fragments for both 16-row subtiles
    bfrag qf[2][2];
    #pragma unroll
    for (int sub = 0; sub < 2; ++sub)
        #pragma unroll
        for (int kh = 0; kh < 2; ++kh)
            qf[sub][kh] = *(const bfrag*)(Qb + (qt * 32 + sub * 16 + r) * DM + kh * 32 + gq * 8);

    f4 o[2][4] = {};
    float ls[2] = {0.f, 0.f};

    const int nsteps = (qt >= 4 * g2) ? (((qt - 4 * g2) >> 3) + 1) : 0;

    const char* Kbb = (const char*)Ks;
    const char* Vbb = (const char*)Vg;
    const int lo16 = lane << 4;

    auto stage = [&](int s, int buf) {
        const int j0 = s * 8 + g2 * 4;       // first kv tile of this step
        const long long base = (long long)j0 * 4096;
        #pragma unroll
        for (int jr = 0; jr < 4; ++jr) {
            const int st = jr * 4 + wid;     // 1-KB stripe 0..15
            GLOAD16(Kbb + base + st * 1024 + lo16, &smem[buf][st * 1024]);
        }
        #pragma unroll
        for (int jr = 0; jr < 4; ++jr) {
            const int st = jr * 4 + wid;
            GLOAD16(Vbb + base + st * 1024 + lo16, &smem[buf][16384 + st * 1024]);
        }
    };

    int cur = 0;
    if (nsteps > 0) stage(0, 0);
    __syncthreads();

    for (int s = 0; s < nsteps; ++s) {
        if (s + 1 < nsteps) stage(s + 1, cur ^ 1);   // prefetch next step

        const unsigned char* Kr = &smem[cur][wid * 4096];
        const unsigned char* Vr = &smem[cur][16384 + wid * 4096];
        const bfrag kf0 = *(const bfrag*)(Kr + lo16);           // rows r,    ch gq
        const bfrag kf1 = *(const bfrag*)(Kr + 1024 + lo16);    // rows r,    ch 4+gq
        const bfrag kf2 = *(const bfrag*)(Kr + 2048 + lo16);    // rows 16+r, ch gq
        const bfrag kf3 = *(const bfrag*)(Kr + 3072 + lo16);    // rows 16+r, ch 4+gq
        bfrag vf[4];
        #pragma unroll
        for (int dt = 0; dt < 4; ++dt)
            vf[dt] = *(const bfrag*)(Vr + dt * 1024 + lo16);

        const int j = s * 8 + g2 * 4 + wid;  // this wave's kv tile

        f4 s00 = {}, s01 = {}, s10 = {}, s11 = {};   // [sub][kv-half]
        s00 = __builtin_amdgcn_mfma_f32_16x16x32_bf16(kf0, qf[0][0], s00, 0, 0, 0);
        s00 = __builtin_amdgcn_mfma_f32_16x16x32_bf16(kf1, qf[0][1], s00, 0, 0, 0);
        s01 = __builtin_amdgcn_mfma_f32_16x16x32_bf16(kf2, qf[0][0], s01, 0, 0, 0);
        s01 = __builtin_amdgcn_mfma_f32_16x16x32_bf16(kf3, qf[0][1], s01, 0, 0, 0);
        s10 = __builtin_amdgcn_mfma_f32_16x16x32_bf16(kf0, qf[1][0], s10, 0, 0, 0);
        s10 = __builtin_amdgcn_mfma_f32_16x16x32_bf16(kf1, qf[1][1], s10, 0, 0, 0);
        s11 = __builtin_amdgcn_mfma_f32_16x16x32_bf16(kf2, qf[1][0], s11, 0, 0, 0);
        s11 = __builtin_amdgcn_mfma_f32_16x16x32_bf16(kf3, qf[1][1], s11, 0, 0, 0);

        const bool valid = (j <= qt);
        const bool ndiag = (j < qt);
        float p00[4], p01[4], p10[4], p11[4];
        #pragma unroll
        for (int e = 0; e < 4; ++e) {
            const bool kle = (gq * 4 + e <= r);
            p00[e] = (valid && (ndiag || kle)) ? __expf(s00[e]) : 0.f;  // sub0, kv 0..15
            p01[e] = (valid && ndiag)          ? __expf(s01[e]) : 0.f;  // sub0, kv 16..31
            p10[e] = valid                     ? __expf(s10[e]) : 0.f;  // sub1, kv 0..15
            p11[e] = (valid && (ndiag || kle)) ? __expf(s11[e]) : 0.f;  // sub1, kv 16..31
        }
        ls[0] += (p00[0] + p00[1]) + (p00[2] + p00[3]) + (p01[0] + p01[1]) + (p01[2] + p01[3]);
        ls[1] += (p10[0] + p10[1]) + (p10[2] + p10[3]) + (p11[0] + p11[1]) + (p11[2] + p11[3]);

        PW pu0, pu1;                         // sigma pack: slots 0-3 <- h0, 4-7 <- h1
        pu0.w[0] = pack_bf16(p00[0], p00[1]); pu0.w[1] = pack_bf16(p00[2], p00[3]);
        pu0.w[2] = pack_bf16(p01[0], p01[1]); pu0.w[3] = pack_bf16(p01[2], p01[3]);
        pu1.w[0] = pack_bf16(p10[0], p10[1]); pu1.w[1] = pack_bf16(p10[2], p10[3]);
        pu1.w[2] = pack_bf16(p11[0], p11[1]); pu1.w[3] = pack_bf16(p11[2], p11[3]);

        #pragma unroll
        for (int dt = 0; dt < 4; ++dt) {
            o[0][dt] = __builtin_amdgcn_mfma_f32_16x16x32_bf16(pu0.v, vf[dt], o[0][dt], 0, 0, 0);
            o[1][dt] = __builtin_amdgcn_mfma_f32_16x16x32_bf16(pu1.v, vf[dt], o[1][dt], 0, 0, 0);
        }

        __syncthreads();                     // reads done + prefetch landed
        cur ^= 1;
    }

    // ---- epilogue: combine 4 waves' partials (reuse smem) ----
    float* Ol  = (float*)smem;               // [4][32][68] = 34816 B
    float* Lsm = (float*)((unsigned char*)smem + 34816);   // [4][32]
    #pragma unroll
    for (int sub = 0; sub < 2; ++sub) {
        ls[sub] += __shfl_xor(ls[sub], 16, 64);
        ls[sub] += __shfl_xor(ls[sub], 32, 64);
        if (lane < 16) Lsm[wid * 32 + sub * 16 + r] = ls[sub];
        #pragma unroll
        for (int dt = 0; dt < 4; ++dt)
            #pragma unroll
            for (int e = 0; e < 4; ++e)
                Ol[(wid * 32 + sub * 16 + gq * 4 + e) * 68 + dt * 16 + r] = o[sub][dt][e];
    }
    __syncthreads();

    for (int i = tid; i < 32 * 64; i += 256) {
        const int row = i >> 6, col = i & 63;
        const float sum = Ol[(row) * 68 + col] + Ol[(32 + row) * 68 + col]
                        + Ol[(64 + row) * 68 + col] + Ol[(96 + row) * 68 + col];
        Opart[((long long)g2 * SEQ + qt * 32 + row) * DM + col] = sum;
    }
    if (tid < 32) {
        const float l = Lsm[tid] + Lsm[32 + tid] + Lsm[64 + tid] + Lsm[96 + tid];
        Lpart[g2 * SEQ + qt * 32 + tid] = l;
    }
}

// ---------------------------------------------------------------------------
// Kernel 3: out = (O0+O1) / (L0+L1)
// ---------------------------------------------------------------------------
__global__ __launch_bounds__(256) void normalize(
    const float* __restrict__ Opart, const float* __restrict__ Lpart,
    float* __restrict__ out)
{
    const int i = blockIdx.x * 256 + threadIdx.x;     // f4 index
    const f4* O0 = (const f4*)Opart;
    const f4* O1 = O0 + (SEQ * DM / 4);
    const int row = i >> 4;
    const f4 a = O0[i], b2 = O1[i];
    const float inv = 1.0f / (Lpart[row] + Lpart[SEQ + row]);
    f4 res;
    #pragma unroll
    for (int e = 0; e < 4; ++e) res[e] = (a[e] + b2[e]) * inv;
    ((f4*)out)[i] = res;
}

extern "C" void kernel_launch(void* const* d_in, const int* in_sizes, int n_in,
                              void* d_out, int out_size, void* d_ws, size_t ws_size,
                              hipStream_t stream)
{
    (void)in_sizes; (void)n_in; (void)out_size; (void)ws_size;
    const float* x  = (const float*)d_in[0];
    const float* wq = (const float*)d_in[1];
    const float* bq = (const float*)d_in[2];
    const float* wk = (const float*)d_in[3];
    const float* bk = (const float*)d_in[4];
    const float* wv = (const float*)d_in[5];
    const float* bv = (const float*)d_in[6];
    float* out = (float*)d_out;

    __bf16* Qb = (__bf16*)d_ws;                       // [S][64] bf16, 1 MB
    __bf16* Ks = Qb + SEQ * DM;                       // tile-major K, 1 MB
    __bf16* Vg = Ks + SEQ * DM;                       // tile-major sigma V, 1 MB
    float*  Opart = (float*)(Vg + SEQ * DM);          // [2][S][64] f32, 4 MB
    float*  Lpart = Opart + 2 * SEQ * DM;             // [2][S] f32, 64 KB

    qkv_proj<<<512, 256, 0, stream>>>(x, wq, bq, wk, bk, wv, bv, Qb, Ks, Vg);
    flash_attn<<<512, 256, 0, stream>>>(Qb, Ks, Vg, Opart, Lpart);
    normalize<<<SEQ * DM / 4 / 256, 256, 0, stream>>>(Opart, Lpart, out);
}